// Round 4
// baseline (40.164 us; speedup 1.0000x reference)
//
#include <hip/hip_runtime.h>
#include <math.h>

#define NN 1024
#define NE 8192

struct c32 { float x, y; };
__device__ __forceinline__ c32 cmul(c32 a, c32 b)  { return {a.x*b.x - a.y*b.y, a.x*b.y + a.y*b.x}; }
__device__ __forceinline__ c32 cmulc(c32 a, c32 b) { return {a.x*b.x + a.y*b.y, a.y*b.x - a.x*b.y}; } // a*conj(b)
__device__ __forceinline__ c32 cadd(c32 a, c32 b)  { return {a.x + b.x, a.y + b.y}; }

__device__ __forceinline__ float sx(float v, int m)  { return __shfl_xor(v, m, 64); }
__device__ __forceinline__ float sidx(float v, int l){ return __shfl(v, l, 64); }

// PennyLane Rot(phi,theta,omega) = RZ(om) RY(th) RZ(phi)  [verified]
__device__ __forceinline__ void rot2(const float* __restrict__ t3, c32 A[2][2]) {
  float phi = t3[0], th = t3[1], om = t3[2];
  float s, c;   sincosf(0.5f * th, &s, &c);
  float sa, ca; sincosf(0.5f * (phi + om), &sa, &ca);
  float sb, cb; sincosf(0.5f * (phi - om), &sb, &cb);
  A[0][0] = {  ca * c, -sa * c };
  A[0][1] = { -cb * s, -sb * s };
  A[1][0] = {  cb * s, -sb * s };
  A[1][1] = {  ca * c,  sa * c };
}

// ---------------- kernel 1: one-hot index extraction + zero mi/mo [verified] ----------------
__global__ void k_extract(const float* __restrict__ Ri, const float* __restrict__ Ro,
                          int* __restrict__ idx_i, int* __restrict__ idx_o,
                          float* __restrict__ mimo) {
  const int per = NN * NE / 4;
  int tid    = blockIdx.x * blockDim.x + threadIdx.x;
  int stride = gridDim.x * blockDim.x;
  if (tid < (2 * NN * 4) / 4) ((float4*)mimo)[tid] = make_float4(0.f, 0.f, 0.f, 0.f);
  for (int t = tid; t < 2 * per; t += stride) {
    bool first = (t < per);
    const float4* src = first ? (const float4*)Ri : (const float4*)Ro;
    int* dst          = first ? idx_i : idx_o;
    int q = first ? t : t - per;
    float4 v = src[q];
    if (v.x != 0.f || v.y != 0.f || v.z != 0.f || v.w != 0.f) {
      int base = q * 4;
      int n = base >> 13;
      int k = base & (NE - 1);
      if (v.x != 0.f) dst[k + 0] = n;
      if (v.y != 0.f) dst[k + 1] = n;
      if (v.z != 0.f) dst[k + 2] = n;
      if (v.w != 0.f) dst[k + 3] = n;
    }
  }
}

// ---------------- kernel 2: edge-parallel message aggregation [verified] ----------------
__global__ void k_edges(const float* __restrict__ X, const float* __restrict__ e,
                        const int* __restrict__ idx_i, const int* __restrict__ idx_o,
                        float* __restrict__ mi, float* __restrict__ mo) {
  int k = blockIdx.x * blockDim.x + threadIdx.x;
  if (k >= NE) return;
  int ni = idx_i[k], no = idx_o[k];
  float w = e[k];
  float4 xo = ((const float4*)X)[no];
  float4 xi = ((const float4*)X)[ni];
  atomicAdd(&mi[ni * 4 + 0], w * xo.x);
  atomicAdd(&mi[ni * 4 + 1], w * xo.y);
  atomicAdd(&mi[ni * 4 + 2], w * xo.z);
  atomicAdd(&mi[ni * 4 + 3], w * xo.w);
  atomicAdd(&mo[no * 4 + 0], w * xi.x);
  atomicAdd(&mo[no * 4 + 1], w * xi.y);
  atomicAdd(&mo[no * 4 + 2], w * xi.z);
  atomicAdd(&mo[no * 4 + 3], w * xi.w);
}

// ---------------- kernel 3: register/shuffle statevector ----------------
// psi_A: 256 amps, i[5:0]=lane (wires 2..7, bit=7-w), i[7:6]=reg r (wire1=bit6, wire0=bit7).
// psi_B: 16 amps (wires 8..11, bit=11-w), replicated in registers on every lane.
__device__ __forceinline__ void rot_lane(c32* a, const c32 (*U)[2], int lane, int b) {
  int s = (lane >> b) & 1;
  c32 us = s ? U[1][1] : U[0][0];
  c32 up = s ? U[1][0] : U[0][1];
  #pragma unroll
  for (int r = 0; r < 4; r++) {
    c32 p = { sx(a[r].x, 1 << b), sx(a[r].y, 1 << b) };
    a[r] = cadd(cmul(us, a[r]), cmul(up, p));
  }
}

__device__ __forceinline__ void rot_pair(c32& x0, c32& x1, const c32 (*U)[2]) {
  c32 n0 = cadd(cmul(U[0][0], x0), cmul(U[0][1], x1));
  c32 n1 = cadd(cmul(U[1][0], x0), cmul(U[1][1], x1));
  x0 = n0; x1 = n1;
}

__device__ __forceinline__ void cnot_ll(c32* a, int lane, int c, int t) {
  int idx = lane ^ (((lane >> c) & 1) << t);
  #pragma unroll
  for (int r = 0; r < 4; r++) a[r] = { sidx(a[r].x, idx), sidx(a[r].y, idx) };
}

__device__ __forceinline__ void rotB(c32* bb, const c32 (*U)[2], int k) {
  int mask = (1 << k) - 1;
  #pragma unroll
  for (int t = 0; t < 8; t++) {
    int i0 = ((t & ~mask) << 1) | (t & mask);
    int i1 = i0 | (1 << k);
    c32 b0 = bb[i0], b1 = bb[i1];
    bb[i0] = cadd(cmul(U[0][0], b0), cmul(U[0][1], b1));
    bb[i1] = cadd(cmul(U[1][0], b0), cmul(U[1][1], b1));
  }
}

__device__ __forceinline__ void cnotB(c32* bb, int c, int t) {
  int lo = c < t ? c : t, hi = c < t ? t : c;
  int lm = (1 << lo) - 1, hm = (1 << hi) - 1;
  #pragma unroll
  for (int q = 0; q < 4; q++) {
    int x = ((q & ~lm) << 1) | (q & lm);
    x = ((x & ~hm) << 1) | (x & hm);
    int i0 = x | (1 << c), i1 = i0 | (1 << t);
    c32 tmp = bb[i0]; bb[i0] = bb[i1]; bb[i1] = tmp;
  }
}

__global__ void __launch_bounds__(64) k_sv3(const float* __restrict__ X,
                                            const float* __restrict__ theta,
                                            const float* __restrict__ mi,
                                            const float* __restrict__ mo,
                                            float* __restrict__ out) {
  __shared__ c32 R[23][2][2];
  const int lane = threadIdx.x;
  const int n = blockIdx.x;

  if (lane < 23) {
    c32 A[2][2];
    rot2(theta + 3 * lane, A);
    R[lane][0][0] = A[0][0]; R[lane][0][1] = A[0][1];
    R[lane][1][0] = A[1][0]; R[lane][1][1] = A[1][1];
  }

  float4 miv = ((const float4*)mi)[n];
  float4 mov = ((const float4*)mo)[n];
  float4 xv  = ((const float4*)X)[n];
  float ang[12] = { miv.x, miv.y, miv.z, miv.w, mov.x, mov.y, mov.z, mov.w, xv.x, xv.y, xv.z, xv.w };
  float cw[12], sw[12];
  #pragma unroll
  for (int w = 0; w < 12; w++) __sincosf(0.5f * ang[w], &sw[w], &cw[w]);

  // product-state init
  c32 a[4];
  {
    float lfac = 1.f;
    #pragma unroll
    for (int w = 2; w < 8; w++) lfac *= ((lane >> (7 - w)) & 1) ? sw[w] : cw[w];
    a[0] = { cw[0] * cw[1] * lfac, 0.f };
    a[1] = { cw[0] * sw[1] * lfac, 0.f };
    a[2] = { sw[0] * cw[1] * lfac, 0.f };
    a[3] = { sw[0] * sw[1] * lfac, 0.f };
  }
  c32 bb[16];
  #pragma unroll
  for (int i = 0; i < 16; i++) {
    float amp = 1.f;
    #pragma unroll
    for (int w = 8; w < 12; w++) amp *= ((i >> (11 - w)) & 1) ? sw[w] : cw[w];
    bb[i] = { amp, 0.f };
  }
  __syncthreads();   // R ready

  // ---- A circuit (reference gate order within the A group) ----
  // block0 (w0,w1) CNOT 0->1 : bits 7,6 (reg)
  rot_pair(a[0], a[2], R[0]);  rot_pair(a[1], a[3], R[0]);     // rot bit7
  rot_pair(a[0], a[1], R[1]);  rot_pair(a[2], a[3], R[1]);     // rot bit6
  { c32 t = a[2]; a[2] = a[3]; a[3] = t; }                     // CNOT c7->t6
  // block1 (w2,w3) CNOT 3->2 : bits 5,4
  rot_lane(a, R[2], lane, 5);
  rot_lane(a, R[3], lane, 4);
  cnot_ll(a, lane, 4, 5);
  // block2 (w4,w5) CNOT 4->5 : bits 3,2
  rot_lane(a, R[4], lane, 3);
  rot_lane(a, R[5], lane, 2);
  cnot_ll(a, lane, 3, 2);
  // block3 (w6,w7) CNOT 7->6 : bits 1,0
  rot_lane(a, R[6], lane, 1);
  rot_lane(a, R[7], lane, 0);
  cnot_ll(a, lane, 0, 1);
  // block6 (w1,w2) CNOT 1->2 : bits 6,5
  rot_pair(a[0], a[1], R[12]); rot_pair(a[2], a[3], R[12]);    // rot bit6
  rot_lane(a, R[13], lane, 5);
  a[1] = { sx(a[1].x, 32), sx(a[1].y, 32) };                   // CNOT c6(reg)->t5(lane)
  a[3] = { sx(a[3].x, 32), sx(a[3].y, 32) };
  // block7 (w5,w6) CNOT 6->5 : bits 2,1
  rot_lane(a, R[14], lane, 2);
  rot_lane(a, R[15], lane, 1);
  cnot_ll(a, lane, 1, 2);
  // block9 (w2,w5) CNOT 2->5 : bits 5,2
  rot_lane(a, R[18], lane, 5);
  rot_lane(a, R[19], lane, 2);
  cnot_ll(a, lane, 5, 2);
  // final Rot wire4 (bit3) — commutes with block10
  rot_lane(a, R[22], lane, 3);

  // ---- B circuit ----
  rotB(bb, R[8], 3);  rotB(bb, R[9], 2);  cnotB(bb, 3, 2);   // block4 (8,9)  c8->t9
  rotB(bb, R[10], 1); rotB(bb, R[11], 0); cnotB(bb, 0, 1);   // block5 (10,11) c11->t10
  rotB(bb, R[16], 2); rotB(bb, R[17], 1); cnotB(bb, 1, 2);   // block8 (9,10) c10->t9

  // ---- rho5 (wire5 = lane bit 2) ----
  int s5 = (lane >> 2) & 1;
  float p00 = 0.f, p11 = 0.f; c32 p01 = {0.f, 0.f};
  #pragma unroll
  for (int r = 0; r < 4; r++) {
    c32 pr = { sx(a[r].x, 4), sx(a[r].y, 4) };
    float nn = a[r].x * a[r].x + a[r].y * a[r].y;
    c32 cp = cmulc(a[r], pr);
    p00 += s5 ? 0.f : nn;
    p11 += s5 ? nn : 0.f;
    p01.x += s5 ? 0.f : cp.x;
    p01.y += s5 ? 0.f : cp.y;
  }
  #pragma unroll
  for (int m = 1; m < 64; m <<= 1) {
    p00 += sx(p00, m); p11 += sx(p11, m);
    p01.x += sx(p01.x, m); p01.y += sx(p01.y, m);
  }

  // ---- rho9 (wire9 = bit 2 of psi_B), identical on all lanes ----
  float q00 = 0.f, q11 = 0.f; c32 q01 = {0.f, 0.f};
  #pragma unroll
  for (int ao = 0; ao < 8; ao++) {
    int i0 = ((ao & ~3) << 1) | (ao & 3);
    int i1 = i0 | 4;
    c32 b0 = bb[i0], b1 = bb[i1];
    q00 += b0.x * b0.x + b0.y * b0.y;
    q11 += b1.x * b1.x + b1.y * b1.y;
    q01 = cadd(q01, cmulc(b0, b1));
  }

  // ---- final block 10 on (5,9): U4 = CNOT(5->9) * (R20 x R21) [verified math] ----
  c32 U4[4][4];
  #pragma unroll
  for (int i = 0; i < 2; i++)
    #pragma unroll
    for (int p = 0; p < 2; p++)
      #pragma unroll
      for (int j = 0; j < 2; j++)
        #pragma unroll
        for (int q = 0; q < 2; q++)
          U4[2 * i + p][2 * j + q] = cmul(R[20][i][j], R[21][p][q]);
  #pragma unroll
  for (int c = 0; c < 4; c++) { c32 t = U4[2][c]; U4[2][c] = U4[3][c]; U4[3][c] = t; }

  c32 rho5[2][2] = { {{p00, 0.f}, p01}, {{p01.x, -p01.y}, {p11, 0.f}} };
  c32 rho9[2][2] = { {{q00, 0.f}, q01}, {{q01.x, -q01.y}, {q11, 0.f}} };
  float z = 0.f;
  #pragma unroll
  for (int aa = 0; aa < 4; aa++)
    #pragma unroll
    for (int b2 = 0; b2 < 4; b2++) {
      c32 m = {0.f, 0.f};
      #pragma unroll
      for (int i = 0; i < 4; i++) {
        c32 t = cmulc(U4[i][aa], U4[i][b2]);
        if (i & 1) { m.x -= t.x; m.y -= t.y; } else { m = cadd(m, t); }
      }
      c32 rr = cmul(rho5[aa >> 1][b2 >> 1], rho9[aa & 1][b2 & 1]);
      z += m.x * rr.x - m.y * rr.y;
    }

  if (lane == 0) out[n] = 3.14159265358979f * (1.f - z);
}

extern "C" void kernel_launch(void* const* d_in, const int* in_sizes, int n_in,
                              void* d_out, int out_size, void* d_ws, size_t ws_size,
                              hipStream_t stream) {
  (void)in_sizes; (void)n_in; (void)out_size; (void)ws_size;
  const float* X     = (const float*)d_in[0];
  const float* e     = (const float*)d_in[1];
  const float* Ri    = (const float*)d_in[2];
  const float* Ro    = (const float*)d_in[3];
  const float* theta = (const float*)d_in[4];
  float* out = (float*)d_out;

  char* ws = (char*)d_ws;
  int*   idx_i = (int*)(ws);
  int*   idx_o = (int*)(ws + 32768);
  float* mi    = (float*)(ws + 65536);
  float* mo    = (float*)(ws + 65536 + 16384);

  hipLaunchKernelGGL(k_extract, dim3(4096), dim3(256), 0, stream, Ri, Ro, idx_i, idx_o, mi);
  hipLaunchKernelGGL(k_edges,   dim3(NE / 256), dim3(256), 0, stream, X, e, idx_i, idx_o, mi, mo);
  hipLaunchKernelGGL(k_sv3,     dim3(NN), dim3(64), 0, stream, X, theta, mi, mo, out);
}